// Round 1
// 814.232 us; speedup vs baseline: 1.1979x; 1.1979x over previous
//
#include <hip/hip_runtime.h>

namespace {

typedef unsigned short u16;

constexpr int Un = 100000;
constexpr int In = 50000;
constexpr int Nn = 150000;
constexpr int D  = 64;
constexpr int Ln = 3;
constexpr int En = 2000000;
constexpr int CHUNK = 1024;
constexpr int NB = (Nn + CHUNK - 1) / CHUNK;  // 147 scan blocks

__device__ __forceinline__ float bf2f(u16 u) {
    return __uint_as_float(((unsigned)u) << 16);
}
__device__ __forceinline__ u16 f2bf(float f) {
    unsigned u = __float_as_uint(f);
    unsigned r = (u + 0x7FFFu + ((u >> 16) & 1u)) >> 16;
    return (u16)r;
}
__device__ __forceinline__ float bflo(unsigned u) {
    return __uint_as_float(u << 16);
}
__device__ __forceinline__ float bfhi(unsigned u) {
    return __uint_as_float(u & 0xFFFF0000u);
}
__device__ __forceinline__ void bf8(const uint4 q, float* o) {
    o[0] = bflo(q.x); o[1] = bfhi(q.x);
    o[2] = bflo(q.y); o[3] = bfhi(q.y);
    o[4] = bflo(q.z); o[5] = bfhi(q.z);
    o[6] = bflo(q.w); o[7] = bfhi(q.w);
}
__device__ __forceinline__ unsigned pack2(float lo, float hi) {
    return (unsigned)f2bf(lo) | ((unsigned)f2bf(hi) << 16);
}

// count AND record per-edge within-row offset (the atomic return value we
// previously threw away) -> fill pass needs no atomics at all.
__global__ void count_kernel(const int* __restrict__ rows, int* __restrict__ deg,
                             int* __restrict__ eoff) {
    int e = blockIdx.x * blockDim.x + threadIdx.x;
    if (e < En) eoff[e] = atomicAdd(&deg[rows[e]], 1);
}

__global__ void scan_partial(const int* __restrict__ deg, float* __restrict__ d_is,
                             int* __restrict__ bsum) {
    int tid = threadIdx.x;
    int base = blockIdx.x * CHUNK + tid * 4;
    int s = 0;
#pragma unroll
    for (int i = 0; i < 4; ++i) {
        int idx = base + i;
        if (idx < Nn) {
            int d = deg[idx];
            s += d;
            d_is[idx] = d > 0 ? rsqrtf((float)d) : 0.f;
        }
    }
    __shared__ int sh[256];
    sh[tid] = s;
    __syncthreads();
    for (int o = 128; o > 0; o >>= 1) {
        if (tid < o) sh[tid] += sh[tid + o];
        __syncthreads();
    }
    if (tid == 0) bsum[blockIdx.x] = sh[0];
}

__global__ void scan_top(int* __restrict__ bsum, int* __restrict__ row_ptr) {
    __shared__ int sh[256];
    int tid = threadIdx.x;
    int v = (tid < NB) ? bsum[tid] : 0;
    sh[tid] = v;
    __syncthreads();
    for (int o = 1; o < 256; o <<= 1) {
        int t = (tid >= o) ? sh[tid - o] : 0;
        __syncthreads();
        sh[tid] += t;
        __syncthreads();
    }
    if (tid < NB) bsum[tid] = sh[tid] - v;  // exclusive
    if (tid == 255) row_ptr[Nn] = sh[255];  // == En
}

__global__ void scan_final(const int* __restrict__ deg, const int* __restrict__ bsum,
                           int* __restrict__ row_ptr) {
    int tid = threadIdx.x;
    int base = blockIdx.x * CHUNK + tid * 4;
    int v[4];
    int ts = 0;
#pragma unroll
    for (int i = 0; i < 4; ++i) {
        int idx = base + i;
        v[i] = (idx < Nn) ? deg[idx] : 0;
        ts += v[i];
    }
    __shared__ int sh[256];
    sh[tid] = ts;
    __syncthreads();
    for (int o = 1; o < 256; o <<= 1) {
        int t = (tid >= o) ? sh[tid - o] : 0;
        __syncthreads();
        sh[tid] += t;
        __syncthreads();
    }
    int excl = bsum[blockIdx.x] + sh[tid] - ts;
#pragma unroll
    for (int i = 0; i < 4; ++i) {
        int idx = base + i;
        if (idx < Nn) row_ptr[idx] = excl;
        excl += v[i];
    }
}

// atomic-free scatter: position comes from row_ptr gather + precomputed eoff
__global__ void fill_kernel(const int* __restrict__ rows, const int* __restrict__ cols,
                            const int* __restrict__ row_ptr, const int* __restrict__ eoff,
                            int* __restrict__ col_s) {
    int e = blockIdx.x * blockDim.x + threadIdx.x;
    if (e >= En) return;
    col_s[row_ptr[rows[e]] + eoff[e]] = cols[e];
}

// emb0 -> out (acc, f32) and cur (bf16)
__global__ void init_kernel(const float* __restrict__ ue, const float* __restrict__ ie,
                            float* __restrict__ out, u16* __restrict__ cur) {
    int i = (blockIdx.x * 256 + threadIdx.x) * 4;
    if (i >= Nn * D) return;
    const float* src = (i < Un * D) ? (ue + i) : (ie + (i - Un * D));
    float4 v = *(const float4*)src;
    *(float4*)(out + i) = v;
    ushort4 q;
    q.x = f2bf(v.x); q.y = f2bf(v.y); q.z = f2bf(v.z); q.w = f2bf(v.w);
    *(ushort4*)(cur + i) = q;
}

// wave per row; 8 edge-groups of 8 lanes; lane holds dims 8l..8l+7 (one
// dwordx4 per gather -> half the vmem instructions of the 4x16 layout).
__global__ __launch_bounds__(256) void spmm_gnn(const u16* __restrict__ A, u16* __restrict__ B,
                                                const int* __restrict__ row_ptr,
                                                const int* __restrict__ col_s,
                                                const float* __restrict__ d_is,
                                                float* __restrict__ inv_norm) {
    int r = (blockIdx.x * 256 + threadIdx.x) >> 6;
    if (r >= Nn) return;
    int lane = threadIdx.x & 63;
    int g = lane >> 3, l = lane & 7;
    int s = row_ptr[r], t = row_ptr[r + 1];
    float dr = d_is[r];
    float a[8] = {0.f, 0.f, 0.f, 0.f, 0.f, 0.f, 0.f, 0.f};
    int nit = (t - s + 7) >> 3;
#pragma unroll 2
    for (int i = 0; i < nit; ++i) {
        int j = s + i * 8 + g;
        bool valid = j < t;
        int jc = valid ? j : (t - 1);
        int c = col_s[jc];
        float v = valid ? dr * d_is[c] : 0.f;
        uint4 q = *(const uint4*)(A + (size_t)c * D + l * 8);
        float x[8];
        bf8(q, x);
#pragma unroll
        for (int k = 0; k < 8; ++k) a[k] += v * x[k];
    }
    // combine the 8 edge-groups
#pragma unroll
    for (int k = 0; k < 8; ++k) {
        a[k] += __shfl_xor(a[k], 8);
        a[k] += __shfl_xor(a[k], 16);
        a[k] += __shfl_xor(a[k], 32);
    }
    float sq = 0.f;
#pragma unroll
    for (int k = 0; k < 8; ++k) sq += a[k] * a[k];
    sq += __shfl_xor(sq, 1); sq += __shfl_xor(sq, 2); sq += __shfl_xor(sq, 4);
    if (g == 0) {
        uint4 o;
        o.x = pack2(a[0], a[1]); o.y = pack2(a[2], a[3]);
        o.z = pack2(a[4], a[5]); o.w = pack2(a[6], a[7]);
        *(uint4*)(B + (size_t)r * D + l * 8) = o;
        if (l == 0) inv_norm[r] = 1.f / fmaxf(sqrtf(sq), 1e-12f);
    }
}

// merged score+fine, 8x8 layout. A (old cur) and B (gnn) read-only;
// cur_new -> C; acc (f32) += cur_new; fine (f32) to out slot.
__global__ __launch_bounds__(256) void score_fine_kernel(const u16* __restrict__ A,
                                                         const u16* __restrict__ B,
                                                         u16* __restrict__ C,
                                                         const float* __restrict__ inv_norm,
                                                         const int* __restrict__ row_ptr,
                                                         const int* __restrict__ col_s,
                                                         float* __restrict__ out, int layer) {
    int r = (blockIdx.x * 256 + threadIdx.x) >> 6;
    if (r >= Nn) return;
    int lane = threadIdx.x & 63;
    int g = lane >> 3, l = lane & 7;
    int s = row_ptr[r], t = row_ptr[r + 1];
    uint4 qb = *(const uint4*)(B + (size_t)r * D + l * 8);
    float b[8];
    bf8(qb, b);
    float ir = inv_norm[r];
    float rowsum = 0.f;
    float f[8] = {0.f, 0.f, 0.f, 0.f, 0.f, 0.f, 0.f, 0.f};
    int nit = (t - s + 7) >> 3;
#pragma unroll 2
    for (int i = 0; i < nit; ++i) {
        int j = s + i * 8 + g;
        bool valid = j < t;
        int jc = valid ? j : (t - 1);
        int c = col_s[jc];
        uint4 qc = *(const uint4*)(B + (size_t)c * D + l * 8);
        uint4 qa = *(const uint4*)(A + (size_t)c * D + l * 8);
        float inc = inv_norm[c];
        float x[8];
        bf8(qc, x);
        float d = b[0] * x[0] + b[1] * x[1] + b[2] * x[2] + b[3] * x[3]
                + b[4] * x[4] + b[5] * x[5] + b[6] * x[6] + b[7] * x[7];
        d += __shfl_xor(d, 1); d += __shfl_xor(d, 2); d += __shfl_xor(d, 4);
        float sc = (d * ir * inc + 1.f) * 0.5f;
        if (!valid) sc = 0.f;
        rowsum += sc;
        float y[8];
        bf8(qa, y);
#pragma unroll
        for (int k = 0; k < 8; ++k) f[k] += sc * y[k];
    }
    // combine the 8 edge-groups
    rowsum += __shfl_xor(rowsum, 8);
    rowsum += __shfl_xor(rowsum, 16);
    rowsum += __shfl_xor(rowsum, 32);
#pragma unroll
    for (int k = 0; k < 8; ++k) {
        f[k] += __shfl_xor(f[k], 8);
        f[k] += __shfl_xor(f[k], 16);
        f[k] += __shfl_xor(f[k], 32);
    }
    float di = rowsum > 0.f ? 1.f / rowsum : 0.f;
#pragma unroll
    for (int k = 0; k < 8; ++k) f[k] *= di;
    if (g == 0) {
        size_t ro = (size_t)r * D + l * 8;
        float cn[8];
#pragma unroll
        for (int k = 0; k < 8; ++k) cn[k] = b[k] + f[k];
        uint4 qn;
        qn.x = pack2(cn[0], cn[1]); qn.y = pack2(cn[2], cn[3]);
        qn.z = pack2(cn[4], cn[5]); qn.w = pack2(cn[6], cn[7]);
        *(uint4*)(C + ro) = qn;
        float4* av = (float4*)(out + ro);
        float4 a0 = av[0], a1 = av[1];
        a0.x += cn[0]; a0.y += cn[1]; a0.z += cn[2]; a0.w += cn[3];
        a1.x += cn[4]; a1.y += cn[5]; a1.z += cn[6]; a1.w += cn[7];
        av[0] = a0; av[1] = a1;
        size_t fo;
        if (r < Un)
            fo = (size_t)Nn * D + (size_t)layer * Un * D + (size_t)r * D + l * 8;
        else
            fo = (size_t)Nn * D + (size_t)Ln * Un * D + (size_t)layer * In * D
                 + (size_t)(r - Un) * D + l * 8;
        float4 f0, f1;
        f0.x = f[0]; f0.y = f[1]; f0.z = f[2]; f0.w = f[3];
        f1.x = f[4]; f1.y = f[5]; f1.z = f[6]; f1.w = f[7];
        ((float4*)(out + fo))[0] = f0;
        ((float4*)(out + fo))[1] = f1;
    }
}

}  // namespace

extern "C" void kernel_launch(void* const* d_in, const int* in_sizes, int n_in,
                              void* d_out, int out_size, void* d_ws, size_t ws_size,
                              hipStream_t stream) {
    const float* user_emb = (const float*)d_in[0];
    const float* item_emb = (const float*)d_in[1];
    const int* rows = (const int*)d_in[2];
    const int* cols = (const int*)d_in[3];
    float* out = (float*)d_out;

    char* ws = (char*)d_ws;
    size_t off = 0;
    auto alloc = [&](size_t bytes) -> void* {
        void* p = ws + off;
        off += (bytes + 255) & ~size_t(255);
        return p;
    };
    u16*   buf0    = (u16*)  alloc((size_t)Nn * D * 2);   // 19.2 MB
    u16*   buf1    = (u16*)  alloc((size_t)Nn * D * 2);   // 19.2 MB
    u16*   buf2    = (u16*)  alloc((size_t)Nn * D * 2);   // 19.2 MB
    int*   col_s   = (int*)  alloc((size_t)En * 4);       // 8 MB
    int*   deg     = (int*)  alloc((size_t)Nn * 4);
    int*   row_ptr = (int*)  alloc((size_t)(Nn + 1) * 4);
    float* d_is    = (float*)alloc((size_t)Nn * 4);
    float* inv_norm= (float*)alloc((size_t)Nn * 4);
    int*   bsum    = (int*)  alloc(4096);
    // eoff (8 MB) aliases buf1: buf1 is first written by spmm_gnn (layer 0),
    // strictly after fill_kernel has consumed eoff.
    int*   eoff    = (int*)buf1;
    (void)ws_size; (void)in_sizes; (void)n_in; (void)out_size;

    hipMemsetAsync(deg, 0, (size_t)Nn * 4, stream);

    init_kernel<<<(Nn * D / 4 + 255) / 256, 256, 0, stream>>>(user_emb, item_emb, out, buf0);

    const int EB = (En + 255) / 256;
    count_kernel<<<EB, 256, 0, stream>>>(rows, deg, eoff);
    scan_partial<<<NB, 256, 0, stream>>>(deg, d_is, bsum);
    scan_top<<<1, 256, 0, stream>>>(bsum, row_ptr);
    scan_final<<<NB, 256, 0, stream>>>(deg, bsum, row_ptr);
    fill_kernel<<<EB, 256, 0, stream>>>(rows, cols, row_ptr, eoff, col_s);

    const int RB = Nn / 4;  // 37500 blocks, 4 waves/block, 1 wave/row
    u16* P = buf0;  // cur
    u16* Q = buf1;  // gnn
    u16* R = buf2;  // cur_new
    for (int l = 0; l < Ln; ++l) {
        spmm_gnn<<<RB, 256, 0, stream>>>(P, Q, row_ptr, col_s, d_is, inv_norm);
        score_fine_kernel<<<RB, 256, 0, stream>>>(P, Q, R, inv_norm, row_ptr, col_s, out, l);
        u16* t0 = P, *t1 = Q, *t2 = R;
        P = t2; Q = t0; R = t1;  // cur_new becomes cur; old buffers recycled
    }
}

// Round 2
// 792.894 us; speedup vs baseline: 1.2301x; 1.0269x over previous
//
#include <hip/hip_runtime.h>

namespace {

typedef unsigned short u16;
typedef __attribute__((__ext_vector_type__(2))) float f32x2;

constexpr int Un = 100000;
constexpr int In = 50000;
constexpr int Nn = 150000;
constexpr int D  = 64;
constexpr int Ln = 3;
constexpr int En = 2000000;
constexpr int CHUNK = 1024;
constexpr int NB = (Nn + CHUNK - 1) / CHUNK;  // 147 scan blocks

__device__ __forceinline__ u16 f2bf(float f) {
    unsigned u = __float_as_uint(f);
    unsigned r = (u + 0x7FFFu + ((u >> 16) & 1u)) >> 16;
    return (u16)r;
}
__device__ __forceinline__ float bflo(unsigned u) {
    return __uint_as_float(u << 16);
}
__device__ __forceinline__ float bfhi(unsigned u) {
    return __uint_as_float(u & 0xFFFF0000u);
}
__device__ __forceinline__ unsigned pack2(float lo, float hi) {
    return (unsigned)f2bf(lo) | ((unsigned)f2bf(hi) << 16);
}

// packed dual-FP32 FMA (CDNA v_pk_fma_f32)
__device__ __forceinline__ f32x2 pkfma(f32x2 a, f32x2 b, f32x2 c) {
    f32x2 d;
    asm("v_pk_fma_f32 %0, %1, %2, %3" : "=v"(d) : "v"(a), "v"(b), "v"(c));
    return d;
}

// sum across each aligned 8-lane group, pure-VALU DPP (no LDS pipe):
// quad_perm xor1, quad_perm xor2, row_half_mirror (cross-quad within 8)
__device__ __forceinline__ float dpp_add8(float x) {
    x += __uint_as_float((unsigned)__builtin_amdgcn_update_dpp(
        0, (int)__float_as_uint(x), 0xB1, 0xF, 0xF, true));
    x += __uint_as_float((unsigned)__builtin_amdgcn_update_dpp(
        0, (int)__float_as_uint(x), 0x4E, 0xF, 0xF, true));
    x += __uint_as_float((unsigned)__builtin_amdgcn_update_dpp(
        0, (int)__float_as_uint(x), 0x141, 0xF, 0xF, true));
    return x;
}

__device__ __forceinline__ void unp8(uint4 q, f32x2* o) {
    o[0].x = bflo(q.x); o[0].y = bfhi(q.x);
    o[1].x = bflo(q.y); o[1].y = bfhi(q.y);
    o[2].x = bflo(q.z); o[2].y = bfhi(q.z);
    o[3].x = bflo(q.w); o[3].y = bfhi(q.w);
}

// count AND record per-edge within-row offset -> fill needs no atomics.
__global__ void count_kernel(const int* __restrict__ rows, int* __restrict__ deg,
                             int* __restrict__ eoff) {
    int e = blockIdx.x * blockDim.x + threadIdx.x;
    if (e < En) eoff[e] = atomicAdd(&deg[rows[e]], 1);
}

__global__ void scan_partial(const int* __restrict__ deg, float* __restrict__ d_is,
                             int* __restrict__ bsum) {
    int tid = threadIdx.x;
    int base = blockIdx.x * CHUNK + tid * 4;
    int s = 0;
#pragma unroll
    for (int i = 0; i < 4; ++i) {
        int idx = base + i;
        if (idx < Nn) {
            int d = deg[idx];
            s += d;
            d_is[idx] = d > 0 ? rsqrtf((float)d) : 0.f;
        }
    }
    __shared__ int sh[256];
    sh[tid] = s;
    __syncthreads();
    for (int o = 128; o > 0; o >>= 1) {
        if (tid < o) sh[tid] += sh[tid + o];
        __syncthreads();
    }
    if (tid == 0) bsum[blockIdx.x] = sh[0];
}

__global__ void scan_top(int* __restrict__ bsum, int* __restrict__ row_ptr) {
    __shared__ int sh[256];
    int tid = threadIdx.x;
    int v = (tid < NB) ? bsum[tid] : 0;
    sh[tid] = v;
    __syncthreads();
    for (int o = 1; o < 256; o <<= 1) {
        int t = (tid >= o) ? sh[tid - o] : 0;
        __syncthreads();
        sh[tid] += t;
        __syncthreads();
    }
    if (tid < NB) bsum[tid] = sh[tid] - v;  // exclusive
    if (tid == 255) row_ptr[Nn] = sh[255];  // == En
}

__global__ void scan_final(const int* __restrict__ deg, const int* __restrict__ bsum,
                           int* __restrict__ row_ptr) {
    int tid = threadIdx.x;
    int base = blockIdx.x * CHUNK + tid * 4;
    int v[4];
    int ts = 0;
#pragma unroll
    for (int i = 0; i < 4; ++i) {
        int idx = base + i;
        v[i] = (idx < Nn) ? deg[idx] : 0;
        ts += v[i];
    }
    __shared__ int sh[256];
    sh[tid] = ts;
    __syncthreads();
    for (int o = 1; o < 256; o <<= 1) {
        int t = (tid >= o) ? sh[tid - o] : 0;
        __syncthreads();
        sh[tid] += t;
        __syncthreads();
    }
    int excl = bsum[blockIdx.x] + sh[tid] - ts;
#pragma unroll
    for (int i = 0; i < 4; ++i) {
        int idx = base + i;
        if (idx < Nn) row_ptr[idx] = excl;
        excl += v[i];
    }
}

// atomic-free scatter; stores BYTE offsets (c * 128) for direct gather addressing
__global__ void fill_kernel(const int* __restrict__ rows, const int* __restrict__ cols,
                            const int* __restrict__ row_ptr, const int* __restrict__ eoff,
                            int* __restrict__ col_off) {
    int e = blockIdx.x * blockDim.x + threadIdx.x;
    if (e >= En) return;
    col_off[row_ptr[rows[e]] + eoff[e]] = cols[e] << 7;
}

// emb0 -> out (acc, f32) and cur (bf16)
__global__ void init_kernel(const float* __restrict__ ue, const float* __restrict__ ie,
                            float* __restrict__ out, u16* __restrict__ cur) {
    int i = (blockIdx.x * 256 + threadIdx.x) * 4;
    if (i >= Nn * D) return;
    const float* src = (i < Un * D) ? (ue + i) : (ie + (i - Un * D));
    float4 v = *(const float4*)src;
    *(float4*)(out + i) = v;
    ushort4 q;
    q.x = f2bf(v.x); q.y = f2bf(v.y); q.z = f2bf(v.z); q.w = f2bf(v.w);
    *(ushort4*)(cur + i) = q;
}

// wave per row; 8 edge-groups of 8 lanes; lane holds dims 8l..8l+7.
// Writes BOTH plain gnn (Q_) and normalized gnn (Qn_ = gnn * 1/||gnn||).
__global__ __launch_bounds__(256) void spmm_gnn(const u16* __restrict__ A_,
                                                u16* __restrict__ Q_,
                                                u16* __restrict__ Qn_,
                                                const int* __restrict__ row_ptr,
                                                const int* __restrict__ col_off,
                                                const float* __restrict__ d_is) {
    int r = (blockIdx.x * 256 + threadIdx.x) >> 6;
    if (r >= Nn) return;
    int lane = threadIdx.x & 63;
    int g = lane >> 3, l = lane & 7;
    unsigned l16 = (unsigned)l * 16u;
    const char* pA = (const char*)A_;
    const char* pd = (const char*)d_is;
    int s = row_ptr[r], t = row_ptr[r + 1];
    float dr = d_is[r];
    f32x2 z; z.x = 0.f; z.y = 0.f;
    f32x2 a2[4] = {z, z, z, z};
    int deg = t - s;
    int nfull = deg >> 3;
    int rem = deg & 7;
    int jb = s + g;
#pragma unroll 2
    for (int i = 0; i < nfull; ++i) {
        unsigned off = (unsigned)col_off[jb + i * 8];
        float dv = *(const float*)(pd + (off >> 5));  // d_is[c]; c*4 == off>>5
        float v = dr * dv;
        uint4 q = *(const uint4*)(pA + (off + l16));
        f32x2 x2[4];
        unp8(q, x2);
        f32x2 v2; v2.x = v; v2.y = v;
#pragma unroll
        for (int p = 0; p < 4; ++p) a2[p] = pkfma(v2, x2[p], a2[p]);
    }
    if (rem) {
        bool valid = g < rem;
        int jc = valid ? (jb + nfull * 8) : s;
        unsigned off = (unsigned)col_off[jc];
        float dv = *(const float*)(pd + (off >> 5));
        float v = valid ? dr * dv : 0.f;
        uint4 q = *(const uint4*)(pA + (off + l16));
        f32x2 x2[4];
        unp8(q, x2);
        f32x2 v2; v2.x = v; v2.y = v;
#pragma unroll
        for (int p = 0; p < 4; ++p) a2[p] = pkfma(v2, x2[p], a2[p]);
    }
    float a[8] = {a2[0].x, a2[0].y, a2[1].x, a2[1].y,
                  a2[2].x, a2[2].y, a2[3].x, a2[3].y};
#pragma unroll
    for (int k = 0; k < 8; ++k) {
        a[k] += __shfl_xor(a[k], 8);
        a[k] += __shfl_xor(a[k], 16);
        a[k] += __shfl_xor(a[k], 32);
    }
    float sq = 0.f;
#pragma unroll
    for (int k = 0; k < 8; ++k) sq = fmaf(a[k], a[k], sq);
    sq = dpp_add8(sq);
    if (g == 0) {
        float ir = 1.f / fmaxf(sqrtf(sq), 1e-12f);
        unsigned ro = ((unsigned)r << 7) + l16;
        uint4 o;
        o.x = pack2(a[0], a[1]); o.y = pack2(a[2], a[3]);
        o.z = pack2(a[4], a[5]); o.w = pack2(a[6], a[7]);
        *(uint4*)((char*)Q_ + ro) = o;
        uint4 on;
        on.x = pack2(a[0] * ir, a[1] * ir); on.y = pack2(a[2] * ir, a[3] * ir);
        on.z = pack2(a[4] * ir, a[5] * ir); on.w = pack2(a[6] * ir, a[7] * ir);
        *(uint4*)((char*)Qn_ + ro) = on;
    }
}

// merged score+fine. Dot uses pre-normalized Qn rows: sc = 0.5*dot + 0.5.
// A_ (old cur) gathered for fine; Q_ (plain gnn) read per-row for cur_new.
__global__ __launch_bounds__(256) void score_fine_kernel(const u16* __restrict__ A_,
                                                         const u16* __restrict__ Q_,
                                                         const u16* __restrict__ Qn_,
                                                         u16* __restrict__ C_,
                                                         const int* __restrict__ row_ptr,
                                                         const int* __restrict__ col_off,
                                                         float* __restrict__ out, int layer) {
    int r = (blockIdx.x * 256 + threadIdx.x) >> 6;
    if (r >= Nn) return;
    int lane = threadIdx.x & 63;
    int g = lane >> 3, l = lane & 7;
    unsigned l16 = (unsigned)l * 16u;
    const char* pQn = (const char*)Qn_;
    const char* pA  = (const char*)A_;
    int s = row_ptr[r], t = row_ptr[r + 1];
    unsigned ro = ((unsigned)r << 7) + l16;
    uint4 qbn = *(const uint4*)(pQn + ro);
    f32x2 b2[4];
    unp8(qbn, b2);
    f32x2 z; z.x = 0.f; z.y = 0.f;
    f32x2 facc[4] = {z, z, z, z};
    float rowsum = 0.f;
    int deg = t - s;
    int nfull = deg >> 3;
    int rem = deg & 7;
    int jb = s + g;
#pragma unroll 2
    for (int i = 0; i < nfull; ++i) {
        unsigned off = (unsigned)col_off[jb + i * 8];
        unsigned vo = off + l16;
        uint4 qx = *(const uint4*)(pQn + vo);
        uint4 qy = *(const uint4*)(pA + vo);
        f32x2 x2[4];
        unp8(qx, x2);
        f32x2 d2 = pkfma(b2[0], x2[0], z);
        d2 = pkfma(b2[1], x2[1], d2);
        d2 = pkfma(b2[2], x2[2], d2);
        d2 = pkfma(b2[3], x2[3], d2);
        float d = dpp_add8(d2.x + d2.y);
        float sc = fmaf(d, 0.5f, 0.5f);
        rowsum += sc;
        f32x2 y2[4];
        unp8(qy, y2);
        f32x2 sc2; sc2.x = sc; sc2.y = sc;
#pragma unroll
        for (int p = 0; p < 4; ++p) facc[p] = pkfma(sc2, y2[p], facc[p]);
    }
    if (rem) {
        bool valid = g < rem;
        int jc = valid ? (jb + nfull * 8) : s;
        unsigned off = (unsigned)col_off[jc];
        unsigned vo = off + l16;
        uint4 qx = *(const uint4*)(pQn + vo);
        uint4 qy = *(const uint4*)(pA + vo);
        f32x2 x2[4];
        unp8(qx, x2);
        f32x2 d2 = pkfma(b2[0], x2[0], z);
        d2 = pkfma(b2[1], x2[1], d2);
        d2 = pkfma(b2[2], x2[2], d2);
        d2 = pkfma(b2[3], x2[3], d2);
        float d = dpp_add8(d2.x + d2.y);
        float sc = fmaf(d, 0.5f, 0.5f);
        if (!valid) sc = 0.f;
        rowsum += sc;
        f32x2 y2[4];
        unp8(qy, y2);
        f32x2 sc2; sc2.x = sc; sc2.y = sc;
#pragma unroll
        for (int p = 0; p < 4; ++p) facc[p] = pkfma(sc2, y2[p], facc[p]);
    }
    float f[8] = {facc[0].x, facc[0].y, facc[1].x, facc[1].y,
                  facc[2].x, facc[2].y, facc[3].x, facc[3].y};
    rowsum += __shfl_xor(rowsum, 8);
    rowsum += __shfl_xor(rowsum, 16);
    rowsum += __shfl_xor(rowsum, 32);
#pragma unroll
    for (int k = 0; k < 8; ++k) {
        f[k] += __shfl_xor(f[k], 8);
        f[k] += __shfl_xor(f[k], 16);
        f[k] += __shfl_xor(f[k], 32);
    }
    float di = rowsum > 0.f ? 1.f / rowsum : 0.f;
#pragma unroll
    for (int k = 0; k < 8; ++k) f[k] *= di;
    if (g == 0) {
        uint4 qb = *(const uint4*)((const char*)Q_ + ro);
        float b[8] = {bflo(qb.x), bfhi(qb.x), bflo(qb.y), bfhi(qb.y),
                      bflo(qb.z), bfhi(qb.z), bflo(qb.w), bfhi(qb.w)};
        float cn[8];
#pragma unroll
        for (int k = 0; k < 8; ++k) cn[k] = b[k] + f[k];
        uint4 qn;
        qn.x = pack2(cn[0], cn[1]); qn.y = pack2(cn[2], cn[3]);
        qn.z = pack2(cn[4], cn[5]); qn.w = pack2(cn[6], cn[7]);
        *(uint4*)((char*)C_ + ro) = qn;
        float* op = out + (size_t)r * D + l * 8;
        float4 a0 = ((float4*)op)[0], a1 = ((float4*)op)[1];
        a0.x += cn[0]; a0.y += cn[1]; a0.z += cn[2]; a0.w += cn[3];
        a1.x += cn[4]; a1.y += cn[5]; a1.z += cn[6]; a1.w += cn[7];
        ((float4*)op)[0] = a0;
        ((float4*)op)[1] = a1;
        size_t fo;
        if (r < Un)
            fo = (size_t)Nn * D + (size_t)layer * Un * D + (size_t)r * D + l * 8;
        else
            fo = (size_t)Nn * D + (size_t)Ln * Un * D + (size_t)layer * In * D
                 + (size_t)(r - Un) * D + l * 8;
        float4 f0, f1;
        f0.x = f[0]; f0.y = f[1]; f0.z = f[2]; f0.w = f[3];
        f1.x = f[4]; f1.y = f[5]; f1.z = f[6]; f1.w = f[7];
        ((float4*)(out + fo))[0] = f0;
        ((float4*)(out + fo))[1] = f1;
    }
}

}  // namespace

extern "C" void kernel_launch(void* const* d_in, const int* in_sizes, int n_in,
                              void* d_out, int out_size, void* d_ws, size_t ws_size,
                              hipStream_t stream) {
    const float* user_emb = (const float*)d_in[0];
    const float* item_emb = (const float*)d_in[1];
    const int* rows = (const int*)d_in[2];
    const int* cols = (const int*)d_in[3];
    float* out = (float*)d_out;

    char* ws = (char*)d_ws;
    size_t off = 0;
    auto alloc = [&](size_t bytes) -> void* {
        void* p = ws + off;
        off += (bytes + 255) & ~size_t(255);
        return p;
    };
    u16*   buf0    = (u16*)  alloc((size_t)Nn * D * 2);   // P: cur (plain)
    u16*   buf1    = (u16*)  alloc((size_t)Nn * D * 2);   // Q: gnn (plain)
    u16*   buf2    = (u16*)  alloc((size_t)Nn * D * 2);   // Qn: gnn normalized
    u16*   buf3    = (u16*)  alloc((size_t)Nn * D * 2);   // R: cur_new
    int*   col_off = (int*)  alloc((size_t)(En + 8) * 4); // byte offsets c*128
    int*   deg     = (int*)  alloc((size_t)Nn * 4);
    int*   row_ptr = (int*)  alloc((size_t)(Nn + 1) * 4);
    float* d_is    = (float*)alloc((size_t)Nn * 4);
    int*   bsum    = (int*)  alloc(4096);
    // eoff (8 MB) aliases buf2 (Qn): Qn first written by spmm_gnn layer 0,
    // strictly after fill_kernel has consumed eoff.
    int*   eoff    = (int*)buf2;
    (void)ws_size; (void)in_sizes; (void)n_in; (void)out_size;

    hipMemsetAsync(deg, 0, (size_t)Nn * 4, stream);

    init_kernel<<<(Nn * D / 4 + 255) / 256, 256, 0, stream>>>(user_emb, item_emb, out, buf0);

    const int EB = (En + 255) / 256;
    count_kernel<<<EB, 256, 0, stream>>>(rows, deg, eoff);
    scan_partial<<<NB, 256, 0, stream>>>(deg, d_is, bsum);
    scan_top<<<1, 256, 0, stream>>>(bsum, row_ptr);
    scan_final<<<NB, 256, 0, stream>>>(deg, bsum, row_ptr);
    fill_kernel<<<EB, 256, 0, stream>>>(rows, cols, row_ptr, eoff, col_off);

    const int RB = Nn / 4;  // 37500 blocks, 4 waves/block, 1 wave/row
    u16* P = buf0;  // cur
    u16* R = buf3;  // cur_new
    for (int l = 0; l < Ln; ++l) {
        spmm_gnn<<<RB, 256, 0, stream>>>(P, buf1, buf2, row_ptr, col_off, d_is);
        score_fine_kernel<<<RB, 256, 0, stream>>>(P, buf1, buf2, R, row_ptr, col_off, out, l);
        u16* tmp = P; P = R; R = tmp;  // cur_new becomes cur
    }
}

// Round 4
// 788.197 us; speedup vs baseline: 1.2374x; 1.0060x over previous
//
#include <hip/hip_runtime.h>

namespace {

typedef unsigned short u16;
typedef __attribute__((__ext_vector_type__(2))) float f32x2;
typedef __attribute__((__ext_vector_type__(4))) float f32x4;

constexpr int Un = 100000;
constexpr int In = 50000;
constexpr int Nn = 150000;
constexpr int D  = 64;
constexpr int Ln = 3;
constexpr int En = 2000000;
constexpr int CHUNK = 1024;
constexpr int NB = (Nn + CHUNK - 1) / CHUNK;  // 147 scan blocks

__device__ __forceinline__ u16 f2bf(float f) {
    unsigned u = __float_as_uint(f);
    unsigned r = (u + 0x7FFFu + ((u >> 16) & 1u)) >> 16;
    return (u16)r;
}
__device__ __forceinline__ float bflo(unsigned u) {
    return __uint_as_float(u << 16);
}
__device__ __forceinline__ float bfhi(unsigned u) {
    return __uint_as_float(u & 0xFFFF0000u);
}
__device__ __forceinline__ unsigned pack2(float lo, float hi) {
    return (unsigned)f2bf(lo) | ((unsigned)f2bf(hi) << 16);
}

// packed dual-FP32 FMA / ADD (CDNA VOP3P)
__device__ __forceinline__ f32x2 pkfma(f32x2 a, f32x2 b, f32x2 c) {
    f32x2 d;
    asm("v_pk_fma_f32 %0, %1, %2, %3" : "=v"(d) : "v"(a), "v"(b), "v"(c));
    return d;
}
__device__ __forceinline__ f32x2 pkadd(f32x2 a, f32x2 b) {
    f32x2 d;
    asm("v_pk_add_f32 %0, %1, %2" : "=v"(d) : "v"(a), "v"(b));
    return d;
}

// sum across each aligned 8-lane group, pure-VALU DPP (no LDS pipe)
__device__ __forceinline__ float dpp_add8(float x) {
    x += __uint_as_float((unsigned)__builtin_amdgcn_update_dpp(
        0, (int)__float_as_uint(x), 0xB1, 0xF, 0xF, true));
    x += __uint_as_float((unsigned)__builtin_amdgcn_update_dpp(
        0, (int)__float_as_uint(x), 0x4E, 0xF, 0xF, true));
    x += __uint_as_float((unsigned)__builtin_amdgcn_update_dpp(
        0, (int)__float_as_uint(x), 0x141, 0xF, 0xF, true));
    return x;
}

__device__ __forceinline__ void unp8(uint4 q, f32x2* o) {
    o[0].x = bflo(q.x); o[0].y = bfhi(q.x);
    o[1].x = bflo(q.y); o[1].y = bfhi(q.y);
    o[2].x = bflo(q.z); o[2].y = bfhi(q.z);
    o[3].x = bflo(q.w); o[3].y = bfhi(q.w);
}

// count AND record per-edge within-row offset -> fill needs no atomics.
__global__ void count_kernel(const int* __restrict__ rows, int* __restrict__ deg,
                             int* __restrict__ eoff) {
    int e = blockIdx.x * blockDim.x + threadIdx.x;
    if (e < En) eoff[e] = atomicAdd(&deg[rows[e]], 1);
}

__global__ void scan_partial(const int* __restrict__ deg, float* __restrict__ d_is,
                             int* __restrict__ bsum) {
    int tid = threadIdx.x;
    int base = blockIdx.x * CHUNK + tid * 4;
    int s = 0;
#pragma unroll
    for (int i = 0; i < 4; ++i) {
        int idx = base + i;
        if (idx < Nn) {
            int d = deg[idx];
            s += d;
            d_is[idx] = d > 0 ? rsqrtf((float)d) : 0.f;
        }
    }
    __shared__ int sh[256];
    sh[tid] = s;
    __syncthreads();
    for (int o = 128; o > 0; o >>= 1) {
        if (tid < o) sh[tid] += sh[tid + o];
        __syncthreads();
    }
    if (tid == 0) bsum[blockIdx.x] = sh[0];
}

__global__ void scan_top(int* __restrict__ bsum, int* __restrict__ row_ptr) {
    __shared__ int sh[256];
    int tid = threadIdx.x;
    int v = (tid < NB) ? bsum[tid] : 0;
    sh[tid] = v;
    __syncthreads();
    for (int o = 1; o < 256; o <<= 1) {
        int t = (tid >= o) ? sh[tid - o] : 0;
        __syncthreads();
        sh[tid] += t;
        __syncthreads();
    }
    if (tid < NB) bsum[tid] = sh[tid] - v;  // exclusive
    if (tid == 255) row_ptr[Nn] = sh[255];  // == En
}

__global__ void scan_final(const int* __restrict__ deg, const int* __restrict__ bsum,
                           int* __restrict__ row_ptr) {
    int tid = threadIdx.x;
    int base = blockIdx.x * CHUNK + tid * 4;
    int v[4];
    int ts = 0;
#pragma unroll
    for (int i = 0; i < 4; ++i) {
        int idx = base + i;
        v[i] = (idx < Nn) ? deg[idx] : 0;
        ts += v[i];
    }
    __shared__ int sh[256];
    sh[tid] = ts;
    __syncthreads();
    for (int o = 1; o < 256; o <<= 1) {
        int t = (tid >= o) ? sh[tid - o] : 0;
        __syncthreads();
        sh[tid] += t;
        __syncthreads();
    }
    int excl = bsum[blockIdx.x] + sh[tid] - ts;
#pragma unroll
    for (int i = 0; i < 4; ++i) {
        int idx = base + i;
        if (idx < Nn) row_ptr[idx] = excl;
        excl += v[i];
    }
}

// atomic-free scatter; stores BYTE offsets (c * 128)
__global__ void fill_kernel(const int* __restrict__ rows, const int* __restrict__ cols,
                            const int* __restrict__ row_ptr, const int* __restrict__ eoff,
                            int* __restrict__ col_off) {
    int e = blockIdx.x * blockDim.x + threadIdx.x;
    if (e >= En) return;
    col_off[row_ptr[rows[e]] + eoff[e]] = cols[e] << 7;
}

// emb0 -> acc (f32), cur0 (bf16), S0 = d_is*emb0 (bf16, prescaled for spmm)
__global__ void init_kernel(const float* __restrict__ ue, const float* __restrict__ ie,
                            const float* __restrict__ d_is,
                            float* __restrict__ out, u16* __restrict__ cur,
                            u16* __restrict__ S) {
    int i = (blockIdx.x * 256 + threadIdx.x) * 4;
    if (i >= Nn * D) return;
    const float* src = (i < Un * D) ? (ue + i) : (ie + (i - Un * D));
    float4 v = *(const float4*)src;
    *(float4*)(out + i) = v;
    ushort4 q;
    q.x = f2bf(v.x); q.y = f2bf(v.y); q.z = f2bf(v.z); q.w = f2bf(v.w);
    *(ushort4*)(cur + i) = q;
    float ds = d_is[i >> 6];
    ushort4 qs;
    qs.x = f2bf(v.x * ds); qs.y = f2bf(v.y * ds);
    qs.z = f2bf(v.z * ds); qs.w = f2bf(v.w * ds);
    *(ushort4*)(S + i) = qs;
}

// wave per row; 8 edge-groups of 8 lanes; lane holds dims 8l..8l+7.
// Gathers PRESCALED S rows (d_is[c]*cur[c]) -> loop is load + pk_add only.
// Outputs Qn = gnn/||gnn|| (bf16) and normv[r] = max(||gnn||, 1e-12).
__global__ __launch_bounds__(256) void spmm_gnn(const u16* __restrict__ S_,
                                                u16* __restrict__ Qn_,
                                                const int* __restrict__ row_ptr,
                                                const int* __restrict__ col_off,
                                                const float* __restrict__ d_is,
                                                float* __restrict__ normv) {
    int r = (blockIdx.x * 256 + threadIdx.x) >> 6;
    if (r >= Nn) return;
    int lane = threadIdx.x & 63;
    int g = lane >> 3, l = lane & 7;
    unsigned l16 = (unsigned)l * 16u;
    const char* pS = (const char*)S_;
    int s = row_ptr[r], t = row_ptr[r + 1];
    float dr = d_is[r];
    f32x2 z; z.x = 0.f; z.y = 0.f;
    f32x2 a2[4] = {z, z, z, z};
    int deg = t - s;
    int nfull = deg >> 3;
    int rem = deg & 7;
    int jb = s + g;
#pragma unroll 2
    for (int i = 0; i < nfull; ++i) {
        unsigned off = (unsigned)col_off[jb + i * 8];
        uint4 q = *(const uint4*)(pS + (off + l16));
        f32x2 x2[4];
        unp8(q, x2);
#pragma unroll
        for (int p = 0; p < 4; ++p) a2[p] = pkadd(a2[p], x2[p]);
    }
    if (g < rem) {  // group-uniform branch: invalid groups skip the load
        unsigned off = (unsigned)col_off[jb + nfull * 8];
        uint4 q = *(const uint4*)(pS + (off + l16));
        f32x2 x2[4];
        unp8(q, x2);
#pragma unroll
        for (int p = 0; p < 4; ++p) a2[p] = pkadd(a2[p], x2[p]);
    }
    float a[8] = {a2[0].x, a2[0].y, a2[1].x, a2[1].y,
                  a2[2].x, a2[2].y, a2[3].x, a2[3].y};
#pragma unroll
    for (int k = 0; k < 8; ++k) {
        a[k] += __shfl_xor(a[k], 8);
        a[k] += __shfl_xor(a[k], 16);
        a[k] += __shfl_xor(a[k], 32);
    }
    float sq = 0.f;
#pragma unroll
    for (int k = 0; k < 8; ++k) sq = fmaf(a[k], a[k], sq);
    sq = dpp_add8(sq);
    if (g == 0) {
        float gn = dr * sqrtf(sq);          // ||gnn||   (gnn = dr * a)
        float nrm = fmaxf(gn, 1e-12f);
        float scale = dr / nrm;             // Qn = a * scale
        normv[r] = nrm;
        unsigned ro = ((unsigned)r << 7) + l16;
        uint4 on;
        on.x = pack2(a[0] * scale, a[1] * scale);
        on.y = pack2(a[2] * scale, a[3] * scale);
        on.z = pack2(a[4] * scale, a[5] * scale);
        on.w = pack2(a[6] * scale, a[7] * scale);
        *(uint4*)((char*)Qn_ + ro) = on;
    }
}

// merged score+fine. Dot over pre-normalized Qn rows: sc = 0.5*dot + 0.5.
// gnn[r] reconstructed as Qn[r]*normv[r] from live registers (no Q buffer).
// Writes cur_new (C_), acc RMW, fine (nontemporal), and S_next = d_is*cur_new.
__global__ __launch_bounds__(256) void score_fine_kernel(const u16* __restrict__ A_,
                                                         const u16* __restrict__ Qn_,
                                                         u16* __restrict__ C_,
                                                         u16* __restrict__ S_,
                                                         const float* __restrict__ normv,
                                                         const float* __restrict__ d_is,
                                                         const int* __restrict__ row_ptr,
                                                         const int* __restrict__ col_off,
                                                         float* __restrict__ out, int layer) {
    int r = (blockIdx.x * 256 + threadIdx.x) >> 6;
    if (r >= Nn) return;
    int lane = threadIdx.x & 63;
    int g = lane >> 3, l = lane & 7;
    unsigned l16 = (unsigned)l * 16u;
    const char* pQn = (const char*)Qn_;
    const char* pA  = (const char*)A_;
    int s = row_ptr[r], t = row_ptr[r + 1];
    unsigned ro = ((unsigned)r << 7) + l16;
    uint4 qbn = *(const uint4*)(pQn + ro);
    float nrm = normv[r];
    float dsr = d_is[r];
    f32x2 b2[4];
    unp8(qbn, b2);
    f32x2 z; z.x = 0.f; z.y = 0.f;
    f32x2 facc[4] = {z, z, z, z};
    float rowsum = 0.f;
    int deg = t - s;
    int nfull = deg >> 3;
    int rem = deg & 7;
    int jb = s + g;
#pragma unroll 2
    for (int i = 0; i < nfull; ++i) {
        unsigned off = (unsigned)col_off[jb + i * 8];
        unsigned vo = off + l16;
        uint4 qx = *(const uint4*)(pQn + vo);
        uint4 qy = *(const uint4*)(pA + vo);
        f32x2 x2[4];
        unp8(qx, x2);
        f32x2 d2 = pkfma(b2[0], x2[0], z);
        d2 = pkfma(b2[1], x2[1], d2);
        d2 = pkfma(b2[2], x2[2], d2);
        d2 = pkfma(b2[3], x2[3], d2);
        float d = dpp_add8(d2.x + d2.y);
        float sc = fmaf(d, 0.5f, 0.5f);
        rowsum += sc;
        f32x2 y2[4];
        unp8(qy, y2);
        f32x2 sc2; sc2.x = sc; sc2.y = sc;
#pragma unroll
        for (int p = 0; p < 4; ++p) facc[p] = pkfma(sc2, y2[p], facc[p]);
    }
    if (g < rem) {  // group-uniform: invalid groups skip loads entirely
        unsigned off = (unsigned)col_off[jb + nfull * 8];
        unsigned vo = off + l16;
        uint4 qx = *(const uint4*)(pQn + vo);
        uint4 qy = *(const uint4*)(pA + vo);
        f32x2 x2[4];
        unp8(qx, x2);
        f32x2 d2 = pkfma(b2[0], x2[0], z);
        d2 = pkfma(b2[1], x2[1], d2);
        d2 = pkfma(b2[2], x2[2], d2);
        d2 = pkfma(b2[3], x2[3], d2);
        float d = dpp_add8(d2.x + d2.y);
        float sc = fmaf(d, 0.5f, 0.5f);
        rowsum += sc;
        f32x2 y2[4];
        unp8(qy, y2);
        f32x2 sc2; sc2.x = sc; sc2.y = sc;
#pragma unroll
        for (int p = 0; p < 4; ++p) facc[p] = pkfma(sc2, y2[p], facc[p]);
    }
    float f[8] = {facc[0].x, facc[0].y, facc[1].x, facc[1].y,
                  facc[2].x, facc[2].y, facc[3].x, facc[3].y};
    rowsum += __shfl_xor(rowsum, 8);
    rowsum += __shfl_xor(rowsum, 16);
    rowsum += __shfl_xor(rowsum, 32);
#pragma unroll
    for (int k = 0; k < 8; ++k) {
        f[k] += __shfl_xor(f[k], 8);
        f[k] += __shfl_xor(f[k], 16);
        f[k] += __shfl_xor(f[k], 32);
    }
    float di = rowsum > 0.f ? 1.f / rowsum : 0.f;
#pragma unroll
    for (int k = 0; k < 8; ++k) f[k] *= di;
    if (g == 0) {
        float bb[8] = {b2[0].x, b2[0].y, b2[1].x, b2[1].y,
                       b2[2].x, b2[2].y, b2[3].x, b2[3].y};
        float cn[8];
#pragma unroll
        for (int k = 0; k < 8; ++k) cn[k] = fmaf(bb[k], nrm, f[k]);  // gnn + fine
        uint4 qn;
        qn.x = pack2(cn[0], cn[1]); qn.y = pack2(cn[2], cn[3]);
        qn.z = pack2(cn[4], cn[5]); qn.w = pack2(cn[6], cn[7]);
        *(uint4*)((char*)C_ + ro) = qn;
        if (layer != Ln - 1) {  // prescaled cur_new for next layer's spmm
            uint4 qs;
            qs.x = pack2(cn[0] * dsr, cn[1] * dsr);
            qs.y = pack2(cn[2] * dsr, cn[3] * dsr);
            qs.z = pack2(cn[4] * dsr, cn[5] * dsr);
            qs.w = pack2(cn[6] * dsr, cn[7] * dsr);
            *(uint4*)((char*)S_ + ro) = qs;
        }
        float* op = out + (size_t)r * D + l * 8;
        float4 a0 = ((float4*)op)[0], a1 = ((float4*)op)[1];
        a0.x += cn[0]; a0.y += cn[1]; a0.z += cn[2]; a0.w += cn[3];
        a1.x += cn[4]; a1.y += cn[5]; a1.z += cn[6]; a1.w += cn[7];
        ((float4*)op)[0] = a0;
        ((float4*)op)[1] = a1;
        size_t fo;
        if (r < Un)
            fo = (size_t)Nn * D + (size_t)layer * Un * D + (size_t)r * D + l * 8;
        else
            fo = (size_t)Nn * D + (size_t)Ln * Un * D + (size_t)layer * In * D
                 + (size_t)(r - Un) * D + l * 8;
        f32x4 f0, f1;
        f0.x = f[0]; f0.y = f[1]; f0.z = f[2]; f0.w = f[3];
        f1.x = f[4]; f1.y = f[5]; f1.z = f[6]; f1.w = f[7];
        __builtin_nontemporal_store(f0, (f32x4*)(out + fo));
        __builtin_nontemporal_store(f1, (f32x4*)(out + fo) + 1);
    }
}

}  // namespace

extern "C" void kernel_launch(void* const* d_in, const int* in_sizes, int n_in,
                              void* d_out, int out_size, void* d_ws, size_t ws_size,
                              hipStream_t stream) {
    const float* user_emb = (const float*)d_in[0];
    const float* item_emb = (const float*)d_in[1];
    const int* rows = (const int*)d_in[2];
    const int* cols = (const int*)d_in[3];
    float* out = (float*)d_out;

    char* ws = (char*)d_ws;
    size_t off = 0;
    auto alloc = [&](size_t bytes) -> void* {
        void* p = ws + off;
        off += (bytes + 255) & ~size_t(255);
        return p;
    };
    u16*   buf0    = (u16*)  alloc((size_t)Nn * D * 2);   // P: cur (plain)
    u16*   buf1    = (u16*)  alloc((size_t)Nn * D * 2);   // R: cur_new (plain)
    u16*   buf2    = (u16*)  alloc((size_t)Nn * D * 2);   // Qn: normalized gnn
    u16*   buf3    = (u16*)  alloc((size_t)Nn * D * 2);   // S: prescaled cur
    int*   col_off = (int*)  alloc((size_t)(En + 8) * 4); // byte offsets c*128
    int*   deg     = (int*)  alloc((size_t)Nn * 4);
    int*   row_ptr = (int*)  alloc((size_t)(Nn + 1) * 4);
    float* d_is    = (float*)alloc((size_t)Nn * 4);
    float* normv   = (float*)alloc((size_t)Nn * 4);
    int*   bsum    = (int*)  alloc(4096);
    // eoff (8 MB) aliases buf2 (Qn): Qn first written by spmm_gnn layer 0,
    // strictly after fill_kernel has consumed eoff.
    int*   eoff    = (int*)buf2;
    (void)ws_size; (void)in_sizes; (void)n_in; (void)out_size;

    hipMemsetAsync(deg, 0, (size_t)Nn * 4, stream);

    const int EB = (En + 255) / 256;
    count_kernel<<<EB, 256, 0, stream>>>(rows, deg, eoff);
    scan_partial<<<NB, 256, 0, stream>>>(deg, d_is, bsum);
    scan_top<<<1, 256, 0, stream>>>(bsum, row_ptr);
    scan_final<<<NB, 256, 0, stream>>>(deg, bsum, row_ptr);
    fill_kernel<<<EB, 256, 0, stream>>>(rows, cols, row_ptr, eoff, col_off);
    // init after scan_partial (needs d_is for the prescaled S0)
    init_kernel<<<(Nn * D / 4 + 255) / 256, 256, 0, stream>>>(user_emb, item_emb, d_is,
                                                              out, buf0, buf3);

    const int RB = Nn / 4;  // 37500 blocks, 4 waves/block, 1 wave/row
    u16* P = buf0;  // cur (plain)
    u16* R = buf1;  // cur_new (plain)
    u16* Qn = buf2;
    u16* S  = buf3; // prescaled cur for spmm (rewritten by score each layer)
    for (int l = 0; l < Ln; ++l) {
        spmm_gnn<<<RB, 256, 0, stream>>>(S, Qn, row_ptr, col_off, d_is, normv);
        score_fine_kernel<<<RB, 256, 0, stream>>>(P, Qn, R, S, normv, d_is,
                                                  row_ptr, col_off, out, l);
        u16* tmp = P; P = R; R = tmp;  // cur_new becomes cur
    }
}